// Round 9
// baseline (528.273 us; speedup 1.0000x reference)
//
#include <hip/hip_runtime.h>
#include <math.h>

// STC loss forward on MI355X — Round 9: merged-state log-domain scan with
// wave_shr:1 DPP lane shift.
//
// R8 post-mortem: __builtin_amdgcn_writelane not declared in this ROCm ->
// compile fail. Fix: CDNA retains gfx9 wave-level DPP; dpp_ctrl 0x138 =
// wave_shr:1 shifts the whole wave64 by one lane in ONE full-rate VALU op
// (lane 0 -> bound_ctrl 0), replacing ds_bpermute (~100+ cy LDS pipe) on the
// loop-carried chain. Rest is R8's design:
//  - exact state merge: A = log(e^E + e^S); E'/S' share sA, so
//    A' = sA + lq with q = p_blank + wt(s(1+1e-7) - p_tok) from K1.
//    8 transcendentals/step (was 10 in R7), ~18 VALU.
//  - K1: one wave per t-row, no barriers, coalesced 16B stores.
//
// Per column k (lane j owns cols 2j, 2j+1), nats:
//   m = max(A, P)          (P = O_{k-1} prev step)
//   eA = exp(A-m); eP = exp(P-m)
//   A' = m + log(eA+eP) + lq_k
//   O' = m + log(max(sk*eP + eA, 1e-30)) + tok_k
// ACCEPT = LSE(O_99, E_100, S_100) = LSE2(O1@lane49, A0@lane50).
// Dead lanes (>=51) and lane50's O-track ride at -1e30 (absorbing under
// fp32 rounding, never inf/NaN). ws = 51,712,000 B (proven footprint).

#define T_LEN   2000
#define BATCH   32
#define NCLS    128
#define LTGT    100
#define RING    8
#define NEG_INF_F (-1e30f)

// ---------------------------------------------------------------- K1: emissions
// tabA[(b*T+t)*50 + j] = (tok_2j, tok_2j+1, lq_2j, lq_2j+1)
// tabB[b*T+t] = (lq_100, 0)      lq_100 = log(p_blank + wt*s)
__global__ void stc_emit(const float* __restrict__ inputs,   // (T,B,C) log-softmax
                         const int*   __restrict__ targets,  // (B,L)
                         float4*      __restrict__ tabA,
                         float2*      __restrict__ tabB,
                         const float wt)
{
    const int tid  = threadIdx.x;        // 256 = 4 waves; wave w owns row t
    const int lane = tid & 63;
    const int w    = tid >> 6;
    const int t    = blockIdx.x * 4 + w;
    const int b    = blockIdx.y;

    __shared__ float lps[4][NCLS];       // raw log-probs, one row per wave

    const size_t base = ((size_t)t * BATCH + b) * NCLS;
    const float x0 = inputs[base + lane];
    const float x1 = inputs[base + lane + 64];
    lps[w][lane]      = x0;
    lps[w][lane + 64] = x1;

    const float p0 = __expf(x0), p1 = __expf(x1);
    float ps = p0 + p1;
    if (lane == 0) ps -= p0;             // s excludes blank (class 0)
    #pragma unroll
    for (int off = 32; off >= 1; off >>= 1)
        ps += __shfl_xor(ps, off, 64);   // all lanes hold s
    const float pb = __shfl(p0, 0, 64);  // blank prob (lane 0's class 0)

    if (lane < 50) {                     // same-wave LDS RAW: in-order DS pipe
        const int t0 = targets[b * LTGT + 2 * lane];
        const int t1 = targets[b * LTGT + 2 * lane + 1];
        const float lt0 = lps[w][t0], lt1 = lps[w][t1];
        const float aa  = fmaf(wt * (1.0f + 1e-7f), ps, pb);
        const float q0  = fmaf(-wt, __expf(lt0), aa);
        const float q1  = fmaf(-wt, __expf(lt1), aa);
        tabA[((size_t)b * T_LEN + t) * 50 + lane] =
            make_float4(lt0, lt1, __logf(q0), __logf(q1));
    } else if (lane == 50) {
        tabB[(size_t)b * T_LEN + t] = make_float2(__logf(fmaf(wt, ps, pb)), 0.0f);
    }
}

// ---------------------------------------------------------------- lane shift
// lane i <- lane i-1 across the whole wave64: gfx9/CDNA DPP wave_shr:1
// (dpp_ctrl 0x138). bound_ctrl=true -> lane 0 reads 0 (caller overrides).
__device__ __forceinline__ float shift_up1(float x)
{
    return __int_as_float(
        __builtin_amdgcn_update_dpp(0, __float_as_int(x),
                                    0x138, 0xf, 0xf, true));
}

// ---------------------------------------------------------------- K2: scan
__global__ void __launch_bounds__(64)
stc_scan(const float4* __restrict__ tabA,
         const float2* __restrict__ tabB,
         const int*    __restrict__ targets,
         float*        __restrict__ out)
{
    const int b    = blockIdx.x;
    const int lane = threadIdx.x;            // lane j owns cols 2j, 2j+1
    const int jc   = (lane < 50) ? lane : 49;
    const bool l50 = (lane == 50);

    // skip gates: col c's odd state takes O_{c-1} iff tgt[c] != tgt[c-1]
    const int tb0 = b * LTGT;
    const int c0 = 2 * lane, c1 = 2 * lane + 1;
    float sk0 = 0.0f, sk1 = 0.0f;
    if (c0 >= 1 && c0 <= 99)
        sk0 = (targets[tb0 + c0] != targets[tb0 + c0 - 1]) ? 1.0f : 0.0f;
    if (c1 <= 99)
        sk1 = (targets[tb0 + c1] != targets[tb0 + c1 - 1]) ? 1.0f : 0.0f;

    // merged log state: A = log(e^E + e^S); init alpha0 = {state0: 1}
    float A0 = (lane == 0) ? 0.0f : NEG_INF_F;
    float O0 = NEG_INF_F, A1 = NEG_INF_F, O1 = NEG_INF_F;
    float p0 = NEG_INF_F;                    // O1 of lane j-1 (prev step)

    const size_t bT = (size_t)b * T_LEN;
    const float4* pA = tabA + bT * 50 + jc;
    const float2* pB = tabB + bT;

    float4 ra[RING];
    float2 rb[RING];
    #pragma unroll
    for (int u = 0; u < RING; ++u) { ra[u] = pA[(size_t)u * 50]; rb[u] = pB[u]; }

    // col 1 first (consumes prev O0); its O1n feeds the DPP shift whose
    // result is needed by col 0 of the NEXT step -> latency sits beside
    // col 0's independent compute.
#define STEP(v, bb) do {                                               \
        const float lq0s = l50 ? (bb).x : (v).z;                       \
        const float m1   = fmaxf(A1, O0);                              \
        const float eA1  = __expf(A1 - m1), eP1 = __expf(O0 - m1);     \
        const float z1   = eA1 + eP1;                                  \
        const float zO1  = fmaxf(fmaf(sk1, eP1, eA1), 1e-30f);         \
        const float A1n  = m1 + __logf(z1) + (v).w;                    \
        const float O1n  = m1 + __logf(zO1) + (v).y;                   \
        const float psh  = shift_up1(O1n);                             \
        const float m0   = fmaxf(A0, p0);                              \
        const float eA0  = __expf(A0 - m0), eP0 = __expf(p0 - m0);     \
        const float z0   = eA0 + eP0;                                  \
        const float zO0  = fmaxf(fmaf(sk0, eP0, eA0), 1e-30f);         \
        A0 = m0 + __logf(z0) + lq0s;                                   \
        O0 = m0 + __logf(zO0) + (v).x;                                 \
        A1 = A1n;  O1 = O1n;                                           \
        p0 = (lane == 0) ? NEG_INF_F : psh;                            \
    } while (0)

    for (int tb = 0; tb < T_LEN; tb += RING) {
        #pragma unroll
        for (int u = 0; u < RING; ++u) {
            STEP(ra[u], rb[u]);
            int tp = tb + u + RING; if (tp > T_LEN - 1) tp = T_LEN - 1;
            ra[u] = pA[(size_t)tp * 50];
            rb[u] = pB[tp];
        }
    }
#undef STEP

    // ACCEPT: LSE(O_99, E_100, S_100) = LSE2(O1@49, A0@50)
    const float vO = __shfl(O1, 49, 64);
    const float vA = __shfl(A0, 50, 64);
    if (lane == 0) {
        const float m = fmaxf(vO, vA);
        const float score = m + __logf(__expf(vO - m) + __expf(vA - m));
        atomicAdd(out, -score / ((float)T_LEN * (float)BATCH));
    }
}

// ---------------------------------------------------------------- launch
extern "C" void kernel_launch(void* const* d_in, const int* in_sizes, int n_in,
                              void* d_out, int out_size, void* d_ws, size_t ws_size,
                              hipStream_t stream)
{
    const float* inputs  = (const float*)d_in[0];   // (2000,32,128) f32
    const int*   targets = (const int*)d_in[1];     // (32,100) i32
    float*       out     = (float*)d_out;           // scalar f32

    float4* tabA = (float4*)d_ws;                                   // 51.2 MB
    float2* tabB = (float2*)((char*)d_ws + (size_t)BATCH * T_LEN * 50 * 16);

    // wt = WLAST + (W0-WLAST)*exp(-NSTEP*ln2/THALF)
    const float wt = (float)(0.1 + 0.9 * exp(-log(2.0) / 10000.0));

    (void)hipMemsetAsync(out, 0, sizeof(float), stream);
    stc_emit<<<dim3(T_LEN / 4, BATCH), dim3(256), 0, stream>>>(inputs, targets,
                                                               tabA, tabB, wt);
    stc_scan<<<dim3(BATCH), dim3(64), 0, stream>>>(tabA, tabB, targets, out);
}

// Round 10
// 458.191 us; speedup vs baseline: 1.1530x; 1.1530x over previous
//
#include <hip/hip_runtime.h>
#include <math.h>

// STC loss forward on MI355X — Round 10: register-pinned prefetch ring.
//
// R9 post-mortem: scan unchanged (447 us, ~536 cy/step) despite fewer
// transcendentals + DPP hop => bottleneck was never issue. VGPR_Count=52
// but the 8-deep ring needs 48 live VGPRs => compiler SANK each ring load
// to just before its use: prefetch distance ~0, full L2/L3 latency
// (~300-450 cy) exposed per step. R2/R7/R9 all converge to ~500 cy/step
// because all do an unpinned per-step global load.
// Fix: 16-deep ring + asm volatile("" ::: "memory") at each round end —
// loads are pinned inside their round (issue->use distance 16..31 steps),
// forcing the ring into registers. Worst-case residual wait: newest load
// of round r consumed first in round r+1 -> one L2 latency per 16 steps.
//
// Emit kernel: one wave per (t,b) row, grid 2000x32 = 64000 waves ->
// ~8 waves/SIMD TLP (was 4 waves/block, ~80 us at a 13 us roofline).
//
// Scan math unchanged from R9 (absmax 0.0): merged state A=log(e^E+e^S),
//   m=max(A,P); A'=m+log(eA+eP)+lq; O'=m+log(max(sk*eP+eA,1e-30))+tok;
// lane j owns cols 2j,2j+1; cross-lane hop = DPP wave_shr:1.
// ws = 51,712,000 B (proven footprint: tabA 50xfloat4 + tabB float2).

#define T_LEN   2000
#define BATCH   32
#define NCLS    128
#define LTGT    100
#define RING    16
#define NEG_INF_F (-1e30f)

// ---------------------------------------------------------------- K1: emissions
// tabA[(b*T+t)*50 + j] = (tok_2j, tok_2j+1, lq_2j, lq_2j+1)
// tabB[b*T+t] = (lq_100, 0)      lq_100 = log(p_blank + wt*s)
__global__ void __launch_bounds__(64)
stc_emit(const float* __restrict__ inputs,   // (T,B,C) log-softmax
         const int*   __restrict__ targets,  // (B,L)
         float4*      __restrict__ tabA,
         float2*      __restrict__ tabB,
         const float wt)
{
    const int t    = blockIdx.x;
    const int b    = blockIdx.y;
    const int lane = threadIdx.x;        // 64 threads = 1 wave per (t,b) row

    __shared__ float lps[NCLS];          // raw log-probs

    const size_t base = ((size_t)t * BATCH + b) * NCLS;
    const float2 x = *(const float2*)(inputs + base + 2 * lane);
    *(float2*)&lps[2 * lane] = x;        // same-wave DS: in-order, no barrier

    const float ex = __expf(x.x), ey = __expf(x.y);
    float ps = (lane == 0) ? ey : (ex + ey);   // s excludes blank (class 0)
    #pragma unroll
    for (int off = 32; off >= 1; off >>= 1)
        ps += __shfl_xor(ps, off, 64);
    const float pb = __shfl(ex, 0, 64);  // blank prob

    if (lane < 50) {
        const int t0 = targets[b * LTGT + 2 * lane];
        const int t1 = targets[b * LTGT + 2 * lane + 1];
        const float lt0 = lps[t0], lt1 = lps[t1];
        const float aa  = fmaf(wt * (1.0f + 1e-7f), ps, pb);
        const float q0  = fmaf(-wt, __expf(lt0), aa);
        const float q1  = fmaf(-wt, __expf(lt1), aa);
        tabA[((size_t)b * T_LEN + t) * 50 + lane] =
            make_float4(lt0, lt1, __logf(q0), __logf(q1));
    } else if (lane == 50) {
        tabB[(size_t)b * T_LEN + t] = make_float2(__logf(fmaf(wt, ps, pb)), 0.0f);
    }
}

// ---------------------------------------------------------------- lane shift
// lane i <- lane i-1 across the wave64: DPP wave_shr:1 (0x138), one VALU op.
__device__ __forceinline__ float shift_up1(float x)
{
    return __int_as_float(
        __builtin_amdgcn_update_dpp(0, __float_as_int(x),
                                    0x138, 0xf, 0xf, true));
}

// ---------------------------------------------------------------- K2: scan
__global__ void __launch_bounds__(64)
stc_scan(const float4* __restrict__ tabA,
         const float2* __restrict__ tabB,
         const int*    __restrict__ targets,
         float*        __restrict__ out)
{
    const int b    = blockIdx.x;
    const int lane = threadIdx.x;            // lane j owns cols 2j, 2j+1
    const int jc   = (lane < 50) ? lane : 49;
    const bool l50 = (lane == 50);

    // skip gates: col c's odd state takes O_{c-1} iff tgt[c] != tgt[c-1]
    const int tb0 = b * LTGT;
    const int c0 = 2 * lane, c1 = 2 * lane + 1;
    float sk0 = 0.0f, sk1 = 0.0f;
    if (c0 >= 1 && c0 <= 99)
        sk0 = (targets[tb0 + c0] != targets[tb0 + c0 - 1]) ? 1.0f : 0.0f;
    if (c1 <= 99)
        sk1 = (targets[tb0 + c1] != targets[tb0 + c1 - 1]) ? 1.0f : 0.0f;

    // merged log state: A = log(e^E + e^S); init alpha0 = {state0: 1}
    float A0 = (lane == 0) ? 0.0f : NEG_INF_F;
    float O0 = NEG_INF_F, A1 = NEG_INF_F, O1 = NEG_INF_F;
    float p0 = NEG_INF_F;                    // O1 of lane j-1 (prev step)

    const size_t bT = (size_t)b * T_LEN;
    const float4* pA = tabA + bT * 50 + jc;
    const float2* pB = tabB + bT;

    float4 ra[RING];
    float2 rb[RING];
    #pragma unroll
    for (int u = 0; u < RING; ++u) { ra[u] = pA[(size_t)u * 50]; rb[u] = pB[u]; }
    asm volatile("" ::: "memory");           // pin prologue loads

#define STEP(v, bb) do {                                               \
        const float lq0s = l50 ? (bb).x : (v).z;                       \
        const float m1   = fmaxf(A1, O0);                              \
        const float eA1  = __expf(A1 - m1), eP1 = __expf(O0 - m1);     \
        const float z1   = eA1 + eP1;                                  \
        const float zO1  = fmaxf(fmaf(sk1, eP1, eA1), 1e-30f);         \
        const float A1n  = m1 + __logf(z1) + (v).w;                    \
        const float O1n  = m1 + __logf(zO1) + (v).y;                   \
        const float psh  = shift_up1(O1n);                             \
        const float m0   = fmaxf(A0, p0);                              \
        const float eA0  = __expf(A0 - m0), eP0 = __expf(p0 - m0);     \
        const float z0   = eA0 + eP0;                                  \
        const float zO0  = fmaxf(fmaf(sk0, eP0, eA0), 1e-30f);         \
        A0 = m0 + __logf(z0) + lq0s;                                   \
        O0 = m0 + __logf(zO0) + (v).x;                                 \
        A1 = A1n;  O1 = O1n;                                           \
        p0 = (lane == 0) ? NEG_INF_F : psh;                            \
    } while (0)

    for (int tb = 0; tb < T_LEN; tb += RING) {   // 125 rounds of 16 steps
        #pragma unroll
        for (int u = 0; u < RING; ++u) {
            STEP(ra[u], rb[u]);
            int tp = tb + u + RING; if (tp > T_LEN - 1) tp = T_LEN - 1;
            ra[u] = pA[(size_t)tp * 50];
            rb[u] = pB[tp];
        }
        // Pin: ring loads may not sink below the round boundary (and may not
        // hoist above the previous one) -> issue->use distance 16..31 steps,
        // ring forced register-resident.
        asm volatile("" ::: "memory");
    }
#undef STEP

    // ACCEPT: LSE(O_99, E_100, S_100) = LSE2(O1@49, A0@50)
    const float vO = __shfl(O1, 49, 64);
    const float vA = __shfl(A0, 50, 64);
    if (lane == 0) {
        const float m = fmaxf(vO, vA);
        const float score = m + __logf(__expf(vO - m) + __expf(vA - m));
        atomicAdd(out, -score / ((float)T_LEN * (float)BATCH));
    }
}

// ---------------------------------------------------------------- launch
extern "C" void kernel_launch(void* const* d_in, const int* in_sizes, int n_in,
                              void* d_out, int out_size, void* d_ws, size_t ws_size,
                              hipStream_t stream)
{
    const float* inputs  = (const float*)d_in[0];   // (2000,32,128) f32
    const int*   targets = (const int*)d_in[1];     // (32,100) i32
    float*       out     = (float*)d_out;           // scalar f32

    float4* tabA = (float4*)d_ws;                                   // 51.2 MB
    float2* tabB = (float2*)((char*)d_ws + (size_t)BATCH * T_LEN * 50 * 16);

    // wt = WLAST + (W0-WLAST)*exp(-NSTEP*ln2/THALF)
    const float wt = (float)(0.1 + 0.9 * exp(-log(2.0) / 10000.0));

    (void)hipMemsetAsync(out, 0, sizeof(float), stream);
    stc_emit<<<dim3(T_LEN, BATCH), dim3(64), 0, stream>>>(inputs, targets,
                                                          tabA, tabB, wt);
    stc_scan<<<dim3(BATCH), dim3(64), 0, stream>>>(tabA, tabB, targets, out);
}

// Round 11
// 454.412 us; speedup vs baseline: 1.1625x; 1.0083x over previous
//
#include <hip/hip_runtime.h>
#include <math.h>

// STC loss forward on MI355X — Round 11: LDS double-buffered DMA staging.
//
// R10 post-mortem: ring STILL not register-resident (VGPR=48 < 96 needed;
// 447 cy/step == one exposed L2/L3 latency per step, identical across
// R2/R7/R9/R10). Indexed ring arrays + rotation => scratch; no source-level
// trick pins them. Fix: take the prefetch out of the register file —
// __builtin_amdgcn_global_load_lds DMA (fire-and-forget, cannot be sunk)
// into a double-buffered LDS chunk, explicit s_waitcnt vmcnt(0) ordering.
//
// Chunking: 80 chunks x 25 steps. Per chunk: wait vmcnt(0) (drains chunk c's
// 21 transfers issued last iteration) -> issue chunk c+1 (20x1KB tabA rows +
// 1x256B lq100 track) into the other buffer -> consume 25 steps from LDS
// (ds_read_b128, 4-deep constant-indexed prefetch = SROA-safe). DMA has a
// full chunk (~1500 cy) to land: steady-state stall ~ 0.
//
// Scan math unchanged since R9 (absmax 0.0): merged state A=log(e^E+e^S);
//   m=max(A,P); A'=m+log(eA+eP)+lq; O'=m+log(max(sk*eP+eA,1e-30))+tok;
// lane j owns cols 2j,2j+1; cross-lane hop = DPP wave_shr:1.
// ws: tabA 51,200,000 B + tabB(float) 256,000 B = 51,456,000 <= proven 51.7MB.

#define T_LEN   2000
#define BATCH   32
#define NCLS    128
#define LTGT    100
#define CHUNK   25
#define NCHUNK  80           // T_LEN / CHUNK
#define XFERS   20           // 20 KiB staged >= 25*800 + 224 lane-overread
#define NEG_INF_F (-1e30f)

// ---------------------------------------------------------------- K1: emissions
// tabA[(b*T+t)*50 + j] = (tok_2j, tok_2j+1, lq_2j, lq_2j+1)
// tabB[b*T+t] = lq_100 = log(p_blank + wt*s)
__global__ void __launch_bounds__(64)
stc_emit(const float* __restrict__ inputs,   // (T,B,C) log-softmax
         const int*   __restrict__ targets,  // (B,L)
         float4*      __restrict__ tabA,
         float*       __restrict__ tabB,
         const float wt)
{
    const int t    = blockIdx.x;
    const int b    = blockIdx.y;
    const int lane = threadIdx.x;        // 1 wave per (t,b) row

    __shared__ float lps[NCLS];

    const size_t base = ((size_t)t * BATCH + b) * NCLS;
    const float2 x = *(const float2*)(inputs + base + 2 * lane);
    *(float2*)&lps[2 * lane] = x;        // same-wave DS: in-order, no barrier

    const float ex = __expf(x.x), ey = __expf(x.y);
    float ps = (lane == 0) ? ey : (ex + ey);   // s excludes blank (class 0)
    #pragma unroll
    for (int off = 32; off >= 1; off >>= 1)
        ps += __shfl_xor(ps, off, 64);
    const float pb = __shfl(ex, 0, 64);  // blank prob

    if (lane < 50) {
        const int t0 = targets[b * LTGT + 2 * lane];
        const int t1 = targets[b * LTGT + 2 * lane + 1];
        const float lt0 = lps[t0], lt1 = lps[t1];
        const float aa  = fmaf(wt * (1.0f + 1e-7f), ps, pb);
        const float q0  = fmaf(-wt, __expf(lt0), aa);
        const float q1  = fmaf(-wt, __expf(lt1), aa);
        tabA[((size_t)b * T_LEN + t) * 50 + lane] =
            make_float4(lt0, lt1, __logf(q0), __logf(q1));
    } else if (lane == 50) {
        tabB[(size_t)b * T_LEN + t] = __logf(fmaf(wt, ps, pb));
    }
}

// ---------------------------------------------------------------- async DMA
__device__ __forceinline__ void async16(void* lds, const void* g)
{
    __builtin_amdgcn_global_load_lds(
        (const __attribute__((address_space(1))) unsigned int*)g,
        (__attribute__((address_space(3))) unsigned int*)lds, 16, 0, 0);
}
__device__ __forceinline__ void async4(void* lds, const void* g)
{
    __builtin_amdgcn_global_load_lds(
        (const __attribute__((address_space(1))) unsigned int*)g,
        (__attribute__((address_space(3))) unsigned int*)lds, 4, 0, 0);
}

// lane i <- lane i-1 across the wave64: DPP wave_shr:1, one VALU op.
__device__ __forceinline__ float shift_up1(float x)
{
    return __int_as_float(
        __builtin_amdgcn_update_dpp(0, __float_as_int(x),
                                    0x138, 0xf, 0xf, true));
}

// ---------------------------------------------------------------- K2: scan
__global__ void __launch_bounds__(64)
stc_scan(const float4* __restrict__ tabA,
         const float*  __restrict__ tabB,
         const int*    __restrict__ targets,
         float*        __restrict__ out)
{
    const int b    = blockIdx.x;
    const int lane = threadIdx.x;            // lane j owns cols 2j, 2j+1
    const bool l50 = (lane == 50);

    __shared__ float4 bufA[2][XFERS * 64];   // 2 x 20,480 B
    __shared__ float  bufB[2][64];           // 2 x 256 B

    // skip gates: col c's odd state takes O_{c-1} iff tgt[c] != tgt[c-1]
    const int tb0 = b * LTGT;
    const int c0 = 2 * lane, c1 = 2 * lane + 1;
    float sk0 = 0.0f, sk1 = 0.0f;
    if (c0 >= 1 && c0 <= 99)
        sk0 = (targets[tb0 + c0] != targets[tb0 + c0 - 1]) ? 1.0f : 0.0f;
    if (c1 <= 99)
        sk1 = (targets[tb0 + c1] != targets[tb0 + c1 - 1]) ? 1.0f : 0.0f;

    // merged log state: A = log(e^E + e^S); init alpha0 = {state0: 1}
    float A0 = (lane == 0) ? 0.0f : NEG_INF_F;
    float O0 = NEG_INF_F, A1 = NEG_INF_F, O1 = NEG_INF_F;
    float p0 = NEG_INF_F;                    // O1 of lane j-1 (prev step)

    const char*  gAbase = (const char*)tabA + (size_t)b * T_LEN * 800;
    const float* gBbase = tabB + (size_t)b * T_LEN;

    // issue chunk 0 into buffer 0
    {
        #pragma unroll
        for (int i = 0; i < XFERS; ++i)
            async16(&bufA[0][i * 64],
                    gAbase + (size_t)i * 1024 + (size_t)lane * 16);
        async4(&bufB[0][0], gBbase + lane);
    }

#define STEP(v, bq) do {                                               \
        const float lq0s = l50 ? (bq) : (v).z;                         \
        const float m1   = fmaxf(A1, O0);                              \
        const float eA1  = __expf(A1 - m1), eP1 = __expf(O0 - m1);     \
        const float z1   = eA1 + eP1;                                  \
        const float zO1  = fmaxf(fmaf(sk1, eP1, eA1), 1e-30f);         \
        const float A1n  = m1 + __logf(z1) + (v).w;                    \
        const float O1n  = m1 + __logf(zO1) + (v).y;                   \
        const float psh  = shift_up1(O1n);                             \
        const float m0   = fmaxf(A0, p0);                              \
        const float eA0  = __expf(A0 - m0), eP0 = __expf(p0 - m0);     \
        const float z0   = eA0 + eP0;                                  \
        const float zO0  = fmaxf(fmaf(sk0, eP0, eA0), 1e-30f);         \
        A0 = m0 + __logf(z0) + lq0s;                                   \
        O0 = m0 + __logf(zO0) + (v).x;                                 \
        A1 = A1n;  O1 = O1n;                                           \
        p0 = (lane == 0) ? NEG_INF_F : psh;                            \
    } while (0)

    float4 pf[4];                            // 4-deep, constant-indexed (SROA)
    float  pfq[4];

    for (int c = 0; c < NCHUNK; ++c) {
        const int cb = c & 1;
        // drain chunk c's DMA (issued last iteration / prologue)
        asm volatile("s_waitcnt vmcnt(0)" ::: "memory");
        if (c + 1 < NCHUNK) {                // issue chunk c+1 into other buf
            const char*  gA = gAbase + (size_t)(c + 1) * (CHUNK * 800);
            const float* gB = gBbase + (c + 1) * CHUNK;
            #pragma unroll
            for (int i = 0; i < XFERS; ++i)
                async16(&bufA[cb ^ 1][i * 64],
                        gA + (size_t)i * 1024 + (size_t)lane * 16);
            async4(&bufB[cb ^ 1][0], gB + lane);
        }
        const float4* lA = &bufA[cb][0];     // rows at 50-float4 stride
        const float*  lB = &bufB[cb][0];
        #pragma unroll
        for (int k = 0; k < 4; ++k) { pf[k] = lA[k * 50 + lane]; pfq[k] = lB[k]; }
        #pragma unroll
        for (int u = 0; u < CHUNK; ++u) {
            const float4 v  = pf[u & 3];
            const float  bq = pfq[u & 3];
            if (u + 4 < CHUNK) {             // prefetch 4 rows ahead
                pf[u & 3]  = lA[(u + 4) * 50 + lane];
                pfq[u & 3] = lB[u + 4];
            }
            STEP(v, bq);
        }
    }
#undef STEP

    // ACCEPT: LSE(O_99, E_100, S_100) = LSE2(O1@49, A0@50)
    const float vO = __shfl(O1, 49, 64);
    const float vA = __shfl(A0, 50, 64);
    if (lane == 0) {
        const float m = fmaxf(vO, vA);
        const float score = m + __logf(__expf(vO - m) + __expf(vA - m));
        atomicAdd(out, -score / ((float)T_LEN * (float)BATCH));
    }
}

// ---------------------------------------------------------------- launch
extern "C" void kernel_launch(void* const* d_in, const int* in_sizes, int n_in,
                              void* d_out, int out_size, void* d_ws, size_t ws_size,
                              hipStream_t stream)
{
    const float* inputs  = (const float*)d_in[0];   // (2000,32,128) f32
    const int*   targets = (const int*)d_in[1];     // (32,100) i32
    float*       out     = (float*)d_out;           // scalar f32

    float4* tabA = (float4*)d_ws;                                   // 51.2 MB
    float*  tabB = (float*)((char*)d_ws + (size_t)BATCH * T_LEN * 50 * 16);

    // wt = WLAST + (W0-WLAST)*exp(-NSTEP*ln2/THALF)
    const float wt = (float)(0.1 + 0.9 * exp(-log(2.0) / 10000.0));

    (void)hipMemsetAsync(out, 0, sizeof(float), stream);
    stc_emit<<<dim3(T_LEN, BATCH), dim3(64), 0, stream>>>(inputs, targets,
                                                          tabA, tabB, wt);
    stc_scan<<<dim3(BATCH), dim3(64), 0, stream>>>(tabA, tabB, targets, out);
}

// Round 12
// 329.561 us; speedup vs baseline: 1.6030x; 1.3788x over previous
//
#include <hip/hip_runtime.h>
#include <math.h>

// STC loss forward on MI355X — Round 12: logaddexp math (2 transcendentals
// per column, was 4) + whole-chunk register staging (zero per-step LDS ops).
//
// R11 post-mortem: DMA staging landed (LDS 41KB, VGPR 132, 0 conflicts) but
// still ~473 cy/step. Remaining serial terms: per-step ds_read lgkm exposure,
// 4-transcendental carried chain, ~100 cy issue. Fixes:
//  (1) m=max(A,P) => log(eA+eP) = log1p(exp(-|A-P|)): 1 exp + 1 log/column.
//      O-track: sk=1 -> O'=m+lz+tok (reuses lz); sk=0 -> O'=A+tok (exact,
//      no clamp). One cndmask on a per-lane-constant mask.
//  (2) chunk = 16 steps; after the vmcnt(0) drain, copy the chunk from LDS
//      into 16 NAMED float4 + 16 uniform floats (no arrays -> registers),
//      then run 16 pure-VALU steps.
//  (3) double-buffered global_load_lds DMA (13x1KB + 256B) as in R11.
//
// Per column (lane j owns cols 2j,2j+1; P = O of col-1):
//   m = max(A,P); lz = log(1 + exp(-|A-P|))
//   A' = m + lz + lq;   O' = (sk ? m+lz : A) + tok
// ACCEPT = LSE2(O1@lane49, A0@lane50). ws layout identical to R11 (proven).

#define T_LEN   2000
#define BATCH   32
#define NCLS    128
#define LTGT    100
#define CHUNK   16
#define NCHUNK  125          // T_LEN / CHUNK
#define XFERS   13           // 13 KiB >= 16*800 + lane overread (13,024 B)
#define NEG_INF_F (-1e30f)

// ---------------------------------------------------------------- K1: emissions
// tabA[(b*T+t)*50 + j] = (tok_2j, tok_2j+1, lq_2j, lq_2j+1)
// tabB[b*T+t] = lq_100 = log(p_blank + wt*s)
__global__ void __launch_bounds__(64)
stc_emit(const float* __restrict__ inputs,   // (T,B,C) log-softmax
         const int*   __restrict__ targets,  // (B,L)
         float4*      __restrict__ tabA,
         float*       __restrict__ tabB,
         const float wt)
{
    const int t    = blockIdx.x;
    const int b    = blockIdx.y;
    const int lane = threadIdx.x;        // 1 wave per (t,b) row

    __shared__ float lps[NCLS];

    const size_t base = ((size_t)t * BATCH + b) * NCLS;
    const float2 x = *(const float2*)(inputs + base + 2 * lane);
    *(float2*)&lps[2 * lane] = x;        // same-wave DS: in-order, no barrier

    const float ex = __expf(x.x), ey = __expf(x.y);
    float ps = (lane == 0) ? ey : (ex + ey);   // s excludes blank (class 0)
    #pragma unroll
    for (int off = 32; off >= 1; off >>= 1)
        ps += __shfl_xor(ps, off, 64);
    const float pb = __shfl(ex, 0, 64);  // blank prob

    if (lane < 50) {
        const int t0 = targets[b * LTGT + 2 * lane];
        const int t1 = targets[b * LTGT + 2 * lane + 1];
        const float lt0 = lps[t0], lt1 = lps[t1];
        const float aa  = fmaf(wt * (1.0f + 1e-7f), ps, pb);
        const float q0  = fmaf(-wt, __expf(lt0), aa);
        const float q1  = fmaf(-wt, __expf(lt1), aa);
        tabA[((size_t)b * T_LEN + t) * 50 + lane] =
            make_float4(lt0, lt1, __logf(q0), __logf(q1));
    } else if (lane == 50) {
        tabB[(size_t)b * T_LEN + t] = __logf(fmaf(wt, ps, pb));
    }
}

// ---------------------------------------------------------------- async DMA
__device__ __forceinline__ void async16(void* lds, const void* g)
{
    __builtin_amdgcn_global_load_lds(
        (const __attribute__((address_space(1))) unsigned int*)g,
        (__attribute__((address_space(3))) unsigned int*)lds, 16, 0, 0);
}
__device__ __forceinline__ void async4(void* lds, const void* g)
{
    __builtin_amdgcn_global_load_lds(
        (const __attribute__((address_space(1))) unsigned int*)g,
        (__attribute__((address_space(3))) unsigned int*)lds, 4, 0, 0);
}

// lane i <- lane i-1 across the wave64: DPP wave_shr:1, one VALU op.
__device__ __forceinline__ float shift_up1(float x)
{
    return __int_as_float(
        __builtin_amdgcn_update_dpp(0, __float_as_int(x),
                                    0x138, 0xf, 0xf, true));
}

// ---------------------------------------------------------------- K2: scan
__global__ void __launch_bounds__(64)
stc_scan(const float4* __restrict__ tabA,
         const float*  __restrict__ tabB,
         const int*    __restrict__ targets,
         float*        __restrict__ out)
{
    const int b    = blockIdx.x;
    const int lane = threadIdx.x;            // lane j owns cols 2j, 2j+1
    const bool l50 = (lane == 50);

    __shared__ float4 bufA[2][XFERS * 64];   // 2 x 13,312 B
    __shared__ float  bufB[2][64];           // 2 x 256 B

    // skip gates as per-lane bool masks (cndmask off an SGPR pair)
    const int tb0 = b * LTGT;
    const int c0 = 2 * lane, c1 = 2 * lane + 1;
    bool skb0 = false, skb1 = false;
    if (c0 >= 1 && c0 <= 99)
        skb0 = (targets[tb0 + c0] != targets[tb0 + c0 - 1]);
    if (c1 <= 99)
        skb1 = (targets[tb0 + c1] != targets[tb0 + c1 - 1]);

    // merged log state: A = log(e^E + e^S); init alpha0 = {state0: 1}
    float A0 = (lane == 0) ? 0.0f : NEG_INF_F;
    float O0 = NEG_INF_F, A1 = NEG_INF_F, O1 = NEG_INF_F;
    float p0 = NEG_INF_F;                    // O1 of lane j-1 (prev step)

    const char*  gAbase = (const char*)tabA + (size_t)b * T_LEN * 800;
    const float* gBbase = tabB + (size_t)b * T_LEN;

    // issue chunk 0 into buffer 0
    #pragma unroll
    for (int i = 0; i < XFERS; ++i)
        async16(&bufA[0][i * 64], gAbase + (size_t)i * 1024 + (size_t)lane * 16);
    async4(&bufB[0][0], gBbase + lane);

#define STEP(v, bq) do {                                               \
        /* col 1 (its O1n feeds next step's col0 via DPP) */           \
        const float m1  = fmaxf(A1, O0);                               \
        const float e1  = __expf(-fabsf(A1 - O0));                     \
        const float lz1 = __logf(1.0f + e1);                           \
        const float ml1 = m1 + lz1;                                    \
        const float O1n = (skb1 ? ml1 : A1) + (v).y;                   \
        const float psh = shift_up1(O1n);                              \
        A1 = ml1 + (v).w;                                              \
        O1 = O1n;                                                      \
        /* col 0 */                                                    \
        const float m0  = fmaxf(A0, p0);                               \
        const float e0  = __expf(-fabsf(A0 - p0));                     \
        const float lz0 = __logf(1.0f + e0);                           \
        const float ml0 = m0 + lz0;                                    \
        const float lq0s = l50 ? (bq) : (v).z;                         \
        O0 = (skb0 ? ml0 : A0) + (v).x;                                \
        A0 = ml0 + lq0s;                                               \
        p0 = (lane == 0) ? NEG_INF_F : psh;                            \
    } while (0)

    for (int c = 0; c < NCHUNK; ++c) {
        const int cb = c & 1;
        // drain chunk c's DMA (issued previous iteration / prologue)
        asm volatile("s_waitcnt vmcnt(0)" ::: "memory");
        if (c + 1 < NCHUNK) {                // issue chunk c+1 into other buf
            const char*  gA = gAbase + (size_t)(c + 1) * (CHUNK * 800);
            const float* gB = gBbase + (c + 1) * CHUNK;
            #pragma unroll
            for (int i = 0; i < XFERS; ++i)
                async16(&bufA[cb ^ 1][i * 64],
                        gA + (size_t)i * 1024 + (size_t)lane * 16);
            async4(&bufB[cb ^ 1][0], gB + lane);
        }
        const float4* lA = &bufA[cb][0];     // rows at 50-float4 stride
        const float*  lB = &bufB[cb][0];

        // stage whole chunk into NAMED registers (no arrays -> no scratch)
#define LOADK(k) const float4 v##k = lA[k * 50 + lane]; const float q##k = lB[k];
        LOADK(0)  LOADK(1)  LOADK(2)  LOADK(3)
        LOADK(4)  LOADK(5)  LOADK(6)  LOADK(7)
        LOADK(8)  LOADK(9)  LOADK(10) LOADK(11)
        LOADK(12) LOADK(13) LOADK(14) LOADK(15)
#undef LOADK
        STEP(v0, q0);   STEP(v1, q1);   STEP(v2, q2);   STEP(v3, q3);
        STEP(v4, q4);   STEP(v5, q5);   STEP(v6, q6);   STEP(v7, q7);
        STEP(v8, q8);   STEP(v9, q9);   STEP(v10, q10); STEP(v11, q11);
        STEP(v12, q12); STEP(v13, q13); STEP(v14, q14); STEP(v15, q15);
    }
#undef STEP

    // ACCEPT: LSE(O_99, E_100, S_100) = LSE2(O1@49, A0@50)
    const float vO = __shfl(O1, 49, 64);
    const float vA = __shfl(A0, 50, 64);
    if (lane == 0) {
        const float m  = fmaxf(vO, vA);
        const float lz = __logf(1.0f + __expf(-fabsf(vO - vA)));
        atomicAdd(out, -(m + lz) / ((float)T_LEN * (float)BATCH));
    }
}

// ---------------------------------------------------------------- launch
extern "C" void kernel_launch(void* const* d_in, const int* in_sizes, int n_in,
                              void* d_out, int out_size, void* d_ws, size_t ws_size,
                              hipStream_t stream)
{
    const float* inputs  = (const float*)d_in[0];   // (2000,32,128) f32
    const int*   targets = (const int*)d_in[1];     // (32,100) i32
    float*       out     = (float*)d_out;           // scalar f32

    float4* tabA = (float4*)d_ws;                                   // 51.2 MB
    float*  tabB = (float*)((char*)d_ws + (size_t)BATCH * T_LEN * 50 * 16);

    // wt = WLAST + (W0-WLAST)*exp(-NSTEP*ln2/THALF)
    const float wt = (float)(0.1 + 0.9 * exp(-log(2.0) / 10000.0));

    (void)hipMemsetAsync(out, 0, sizeof(float), stream);
    stc_emit<<<dim3(T_LEN, BATCH), dim3(64), 0, stream>>>(inputs, targets,
                                                          tabA, tabB, wt);
    stc_scan<<<dim3(BATCH), dim3(64), 0, stream>>>(tabA, tabB, targets, out);
}